// Round 4
// baseline (1215.379 us; speedup 1.0000x reference)
//
#include <hip/hip_runtime.h>
#include <math.h>

#define NEGV -1e20f
#define DPAD 132      // diag row stride (s index), 16B-aligned
#define ROWSA 646     // allocated diag rows per batch (rows -2..643)
#define RBOFF 2
#define RB(p,b) ((p) + ((size_t)(b) * ROWSA + RBOFF) * DPAD)

typedef __attribute__((ext_vector_type(4))) float floatx4;
typedef __attribute__((ext_vector_type(8))) short short8;
typedef __attribute__((ext_vector_type(4))) short short4v;

// B=8, T=512, S=128, C=512, S1=129, T1=513, R=19 (hard-coded for this problem)
// Diagonal-major DP arrays: X[b][d][s] = x[s][t] with d = s+t.

__device__ __forceinline__ float lae(float a, float b){
  float mx = fmaxf(a, b);
  float mn = fminf(a, b);
  return mx + __logf(1.f + __expf(mn - mx));   // exp underflows to 0 for big gaps
}

__device__ __forceinline__ short f2bf(float x){  // f32 -> bf16 RNE
  union { float f; unsigned u; } v; v.f = x;
  unsigned r = v.u + 0x7fffu + ((v.u >> 16) & 1u);
  return (short)(r >> 16);
}

__device__ __forceinline__ float fast_tanh(float x){
  x = fminf(fmaxf(x, -15.f), 15.f);
  float e = __expf(2.f * x);
  return (e - 1.f) / (e + 1.f);
}

// ---------- per-row max (+ optional logsumexp) over C=512 ----------
__global__ __launch_bounds__(256) void k_row_stats(
    const float* __restrict__ in, float* __restrict__ outMax, float* __restrict__ outLse)
{
  int row = blockIdx.x;
  const float* r = in + (size_t)row * 512;
  int tid = threadIdx.x;
  float v0 = r[tid], v1 = r[tid + 256];
  float m = fmaxf(v0, v1);
  #pragma unroll
  for (int off = 32; off; off >>= 1) m = fmaxf(m, __shfl_xor(m, off, 64));
  __shared__ float sm[4];
  __shared__ float sbm;
  int wv = tid >> 6;
  if ((tid & 63) == 0) sm[wv] = m;
  __syncthreads();
  if (tid == 0) sbm = fmaxf(fmaxf(sm[0], sm[1]), fmaxf(sm[2], sm[3]));
  __syncthreads();
  float mx = sbm;
  if (tid == 0) outMax[row] = mx;
  if (outLse){
    float s = __expf(v0 - mx) + __expf(v1 - mx);
    #pragma unroll
    for (int off = 32; off; off >>= 1) s += __shfl_xor(s, off, 64);
    __shared__ float sp[4];
    if ((tid & 63) == 0) sp[wv] = s;
    __syncthreads();
    if (tid == 0) outLse[row] = mx + __logf(sp[0] + sp[1] + sp[2] + sp[3]);
  }
}

// ---------- transpose + bf16-convert joiner_w: Wb[d][c] = bf16(W[c][d]) ----------
__global__ __launch_bounds__(256) void k_wb(const float* __restrict__ W, short* __restrict__ Wb){
  int idx = blockIdx.x * 256 + threadIdx.x;   // 262144 total
  int d = idx >> 9, c = idx & 511;
  Wb[idx] = f2bf(W[c * 512 + d]);
}

// ---------- normalizers: norm[b,s,t] = log(dot(exp(lm-lmmax), exp(am-ammax))) + maxes ----------
__global__ __launch_bounds__(256) void k_norm(
    const float* __restrict__ am, const float* __restrict__ lm,
    const float* __restrict__ lmMax, const float* __restrict__ amMax,
    float* __restrict__ normv)
{
  int b = blockIdx.z;
  int s0 = blockIdx.y * 16;
  int t0 = blockIdx.x * 128;
  __shared__ float lmS[16][68];
  __shared__ float amS[128][68];
  int tid = threadIdx.x;
  int ts = tid >> 4, tt = tid & 15;
  float acc[8];
  #pragma unroll
  for (int j = 0; j < 8; ++j) acc[j] = 0.f;

  for (int k0 = 0; k0 < 512; k0 += 64){
    { // stage lm tile 16x64 (exp fused)
      int e = tid * 4;
      int rr = e >> 6, cc = e & 63;
      int s = s0 + rr;
      floatx4 o = {0.f, 0.f, 0.f, 0.f};
      if (s < 129){
        float mx = lmMax[b * 129 + s];
        floatx4 v = *(const floatx4*)(lm + ((size_t)(b * 129 + s)) * 512 + k0 + cc);
        o[0] = __expf(v[0] - mx); o[1] = __expf(v[1] - mx);
        o[2] = __expf(v[2] - mx); o[3] = __expf(v[3] - mx);
      }
      *(floatx4*)&lmS[rr][cc] = o;
    }
    #pragma unroll
    for (int i = 0; i < 8; ++i){ // stage am tile 128x64 (exp fused)
      int e = (tid + i * 256) * 4;
      int rr = e >> 6, cc = e & 63;
      float mx = amMax[b * 512 + t0 + rr];
      floatx4 v = *(const floatx4*)(am + ((size_t)(b * 512 + t0 + rr)) * 512 + k0 + cc);
      floatx4 o;
      o[0] = __expf(v[0] - mx); o[1] = __expf(v[1] - mx);
      o[2] = __expf(v[2] - mx); o[3] = __expf(v[3] - mx);
      *(floatx4*)&amS[rr][cc] = o;
    }
    __syncthreads();
    #pragma unroll 4
    for (int k = 0; k < 64; ++k){
      float a = lmS[ts][k];
      #pragma unroll
      for (int j = 0; j < 8; ++j) acc[j] += a * amS[tt + 16 * j][k];
    }
    __syncthreads();
  }
  int s = s0 + ts;
  if (s < 129){
    float lmx = lmMax[b * 129 + s];
    #pragma unroll
    for (int j = 0; j < 8; ++j){
      int t = t0 + tt + 16 * j;
      normv[((size_t)(b * 129 + s)) * 512 + t] = __logf(acc[j]) + lmx + amMax[b * 512 + t];
    }
  }
}

// ---------- smoothed px/py, written DIAG-major ----------
__global__ __launch_bounds__(256) void k_pxpy(
    const float* __restrict__ am, const float* __restrict__ lm,
    const int* __restrict__ targets, const float* __restrict__ normv,
    const float* __restrict__ lmLse, float* __restrict__ pxd, float* __restrict__ pyd)
{
  int bs = blockIdx.x;           // b*129 + s
  int b = bs / 129, s = bs % 129;
  float lm0 = lm[(size_t)bs * 512];
  float lse = lmLse[bs];
  int sym = 0; float lms = 0.f;
  if (s < 128){ sym = targets[b * 128 + s]; lms = lm[(size_t)bs * 512 + sym]; }
  const float* nrm = normv + (size_t)bs * 512;
  float* pydb = RB(pyd, b);
  float* pxdb = RB(pxd, b);
  for (int t = threadIdx.x; t < 513; t += 256){
    if (t < 512){
      float n = nrm[t];
      float a0 = am[((size_t)(b * 512 + t)) * 512];
      pydb[(size_t)(s + t) * DPAD + s] = 0.75f * (a0 + lm0 - n) + 0.25f * (lm0 - lse);
      if (s < 128){
        float as = am[((size_t)(b * 512 + t)) * 512 + sym];
        pxdb[(size_t)(s + t) * DPAD + s] = 0.75f * (as + lms - n) + 0.25f * (lms - lse);
      }
    } else if (s < 128){
      pxdb[(size_t)(s + 512) * DPAD + s] = NEGV;
    }
  }
}

// ======================================================================
// One-wave-per-batch systolic lattice DP. Lane l owns rows {2l, 2l+1}
// (lane 63 also row 128). All cells on diagonal d depend only on d-1, so
// intra-lane vertical deps are free; the single lane-crossing dep travels
// via one ds_bpermute per step. Operands prefetched distance-2 into NAMED
// registers (no local arrays -> no scratch). Zero barriers.
// ======================================================================

__global__ __launch_bounds__(64) void k_dp_fwd(
    const float* __restrict__ pxd, const float* __restrict__ pyd,
    float* __restrict__ pad, float* __restrict__ tot)
{
  int b = blockIdx.x;
  int l = threadIdx.x;
  const float* pxb = RB(pxd, b);
  const float* pyb = RB(pyd, b);
  float* pab = pad ? RB(pad, b) : nullptr;
  const int a = 2 * l;
  float curA = NEGV, curB = NEGV, curC = NEGV, send = NEGV;
  int paddr = (l - 1) << 2;
  // buffers by content: pxA=row d-1, pxB=row d, pxC=row d+1; pyA=row d-1, pyB=row d
  float2 pxA = *(const float2*)(pxb - 1 * DPAD + a);
  float2 pxB = *(const float2*)(pxb + 0 * DPAD + a);
  float2 pxC = *(const float2*)(pxb + 1 * DPAD + a);
  float2 pyA = *(const float2*)(pyb - 1 * DPAD + a);
  float2 pyB = *(const float2*)(pyb + 0 * DPAD + a);
  float py128A = pyb[-1 * DPAD + 128];
  float py128B = pyb[0 * DPAD + 128];

  for (int d = 0; d <= 640; ++d){
    // prefetch (distance 2)
    float2 pxD = *(const float2*)(pxb + (size_t)(d + 2) * DPAD + a);
    float2 pyC = *(const float2*)(pyb + (size_t)(d + 1) * DPAD + a);
    float py128C = pyb[(size_t)(d + 1) * DPAD + 128];

    float recv = __int_as_float(
        __builtin_amdgcn_ds_bpermute(paddr, __float_as_int(send)));
    int tA = d - a;
    int tC = d - 128;
    // cell A (row a): vertical via recv (pre-added px at source)
    float aaA = (l > 0) ? recv : NEGV;
    float bbA = (tA >= 1) ? curA + pyA.x : NEGV;
    float nvA = lae(aaA, bbA);
    if (l == 0 && d == 0) nvA = 0.f;              // p[0][0]
    // cell B (row a+1): vertical from own cell A (prev step)
    float aaB = curA + pxA.x;
    float bbB = (tA >= 2) ? curB + pyA.y : NEGV;
    float nvB = lae(aaB, bbB);
    // cell C (row 128, lane 63): vertical from own cell B (prev step)
    float aaC = curB + pxA.y;
    float bbC = (tC >= 1) ? curC + py128A : NEGV;
    float nvC = lae(aaC, bbC);
    // commit
    if (tA >= 0 && tA <= 512) curA = nvA;
    if (tA >= 1 && tA <= 513) curB = nvB;
    if (tC >= 0 && tC <= 512) curC = nvC;
    send = curB + pxB.y;                           // p[a+1][tB] + px[a+1][tB]
    if (pab){
      *(float2*)(pab + (size_t)d * DPAD + a) = make_float2(curA, curB);
      if (l == 63) pab[(size_t)d * DPAD + 128] = curC;
    }
    // rotate
    pxA = pxB; pxB = pxC; pxC = pxD;
    pyA = pyB; pyB = pyC;
    py128A = py128B; py128B = py128C;
  }
  if (l == 63) tot[b] = curC;                      // p[128][512]
}

__global__ __launch_bounds__(64) void k_dp_bwd(
    const float* __restrict__ pxd, const float* __restrict__ pyd,
    float* __restrict__ betad)
{
  int b = blockIdx.x;
  int l = threadIdx.x;
  const float* pxb = RB(pxd, b);
  const float* pyb = RB(pyd, b);
  float* beb = RB(betad, b);
  const int a = 2 * l;
  float curA = NEGV, curB = NEGV, curC = NEGV, send = NEGV;
  int paddr = (l + 1) << 2;
  // buffers: pxA=row d, pxB=row d-1 (prefetch distance 2)
  float2 pxA = *(const float2*)(pxb + (size_t)640 * DPAD + a);
  float2 pxB = *(const float2*)(pxb + (size_t)639 * DPAD + a);
  float2 pyA = *(const float2*)(pyb + (size_t)640 * DPAD + a);
  float2 pyB = *(const float2*)(pyb + (size_t)639 * DPAD + a);
  float py128A = pyb[(size_t)640 * DPAD + 128];
  float py128B = pyb[(size_t)639 * DPAD + 128];

  for (int d = 640; d >= 0; --d){
    float2 pxC = *(const float2*)(pxb + (size_t)(d - 2) * DPAD + a);
    float2 pyC = *(const float2*)(pyb + (size_t)(d - 2) * DPAD + a);
    float py128C = pyb[(size_t)(d - 2) * DPAD + 128];

    float recv = __int_as_float(
        __builtin_amdgcn_ds_bpermute(paddr, __float_as_int(send)));
    int tA = d - a;            // row a
    int tB = tA - 1;           // row a+1
    int tC = d - 128;          // row 128
    // cell A (row a): beta[a+1][tA] = own cell B prev step
    float aaA = pxA.x + curB;
    float bbA = (tA <= 511) ? pyA.x + curA : NEGV;
    float nvA = lae(aaA, bbA);
    // cell B (row a+1): beta[a+2][tB] = lane l+1 cell A prev (or own C for l=63)
    float up = (l < 63) ? recv : curC;
    float aaB = pxA.y + up;
    float bbB = (tB <= 511) ? pyA.y + curB : NEGV;
    float nvB = lae(aaB, bbB);
    // cell C (row 128): horizontal only
    float nvC = (tC <= 511) ? py128A + curC : NEGV;
    if (tC == 512) nvC = 0.f;                      // beta[128][512] = 0
    // commit
    if (tA >= 0 && tA <= 512) curA = nvA;
    if (tB >= 0 && tB <= 512) curB = nvB;
    if (tC >= 0 && tC <= 512) curC = nvC;
    send = curA;
    *(float2*)(beb + (size_t)d * DPAD + a) = make_float2(curA, curB);
    if (l == 63) beb[(size_t)d * DPAD + 128] = curC;
    // rotate
    pxA = pxB; pxB = pxC;
    pyA = pyB; pyB = pyC;
    py128A = py128B; py128B = py128C;
  }
}

// ---------- sliding-window argmax over s for each (b,t); grads on the fly ----------
__global__ __launch_bounds__(256) void k_window(
    const float* __restrict__ pxd, const float* __restrict__ pyd,
    const float* __restrict__ pad, const float* __restrict__ betad,
    const float* __restrict__ tots, int* __restrict__ sbr)
{
  __shared__ float tote[129][66];
  int b = blockIdx.x >> 3;
  int t0 = (blockIdx.x & 7) << 6;
  const float* px = RB(pxd, b);
  const float* py = RB(pyd, b);
  const float* pa = RB(pad, b);
  const float* be = RB(betad, b);
  float tv = tots[b];
  int tid = threadIdx.x;
  int wv = tid >> 6, ln = tid & 63;
  for (int dd = wv; dd < 192; dd += 4){
    int d = t0 + dd;
    int slo = dd - 63 > 0 ? dd - 63 : 0;
    int shi = dd < 128 ? dd : 128;
    int s = slo + ln;
    if (s <= shi){
      size_t r0 = (size_t)d * DPAD + s, r1 = (size_t)(d + 1) * DPAD + s;
      float pav = pa[r0];
      float v = __expf(pav + py[r0] + be[r1] - tv);          // gy
      if (s < 128) v += __expf(pav + px[r0] + be[r1 + 1] - tv); // gx
      tote[s][dd - s] = v;
    }
  }
  __syncthreads();
  if (tid < 64){
    int c = tid;
    float win = 0.f;
    for (int s = 0; s < 19; ++s) win += tote[s][c];
    float best = win; int arg = 0;
    for (int w2 = 1; w2 <= 110; ++w2){
      win += tote[w2 + 18][c] - tote[w2 - 1][c];
      if (win > best){ best = win; arg = w2; }   // strict > keeps first-index argmax
    }
    sbr[b * 512 + t0 + c] = arg;
  }
}

// ---------- monotone lower-bound adjust (single reverse pass per batch) ----------
__global__ void k_adjust(const int* __restrict__ sbr, int* __restrict__ sbeg){
  if (threadIdx.x != 0) return;
  int b = blockIdx.x;
  const int* in = sbr + b * 512;
  int* out = sbeg + b * 512;
  int sbm = 1 << 30, ym = 1 << 30;
  for (int t = 511; t >= 0; --t){
    sbm = min(sbm, in[t]);
    int y = 18 * t - sbm;
    ym = min(ym, y);
    int yc = ym > 0 ? ym : 0;
    out[t] = 18 * t - yc;
  }
}

// ---------- joiner: H=tanh(am+lm_pruned) bf16, logits=H@Wb+bias, fused logsumexp epilogue ----------
__global__ __launch_bounds__(256) void k_joiner(
    const float* __restrict__ am, const float* __restrict__ lm,
    const int* __restrict__ targets, const float* __restrict__ bias,
    const short* __restrict__ Wb, const int* __restrict__ sbeg,
    float* __restrict__ pxv, float* __restrict__ pyv)
{
  __shared__ short Hs[32][40];          // 32 rows x 32 k, row stride 40 (bank spread)
  __shared__ int rowSym[32];
  __shared__ int rowAm[32];
  __shared__ int rowLm[32];
  __shared__ float redM[32][4];
  __shared__ float redS[32][4];
  __shared__ float rowMax[32];
  __shared__ float rowNorm[32];

  int tid = threadIdx.x;
  int r0 = blockIdx.x * 32;
  if (tid < 32){
    int row = r0 + tid;
    int g = row / 19;
    int j = row - g * 19;
    int b = g >> 9;
    int t = g & 511;
    int start = sbeg[b * 512 + t];
    int sidx = start + j;               // <= 128 by construction
    rowSym[tid] = (sidx < 128) ? targets[b * 128 + sidx] : 0;
    rowAm[tid] = (b * 512 + t) * 512;
    rowLm[tid] = (b * 129 + sidx) * 512;
  }
  __syncthreads();

  int wv = tid >> 6, lane = tid & 63, q = lane >> 4, ln = lane & 15;
  int colBase = wv * 128 + ln;
  int hr = tid >> 3, kk = (tid & 7) * 4;

  floatx4 acc[2][8];
  #pragma unroll
  for (int mt = 0; mt < 2; ++mt)
    #pragma unroll
    for (int nt = 0; nt < 8; ++nt) acc[mt][nt] = (floatx4){0.f, 0.f, 0.f, 0.f};

  for (int k0 = 0; k0 < 512; k0 += 32){
    { // fused activation staging: 4 elems/thread
      const float* ap = am + (size_t)rowAm[hr] + k0 + kk;
      const float* lp = lm + (size_t)rowLm[hr] + k0 + kk;
      floatx4 a4 = *(const floatx4*)ap;
      floatx4 l4 = *(const floatx4*)lp;
      short4v h;
      h[0] = f2bf(fast_tanh(a4[0] + l4[0]));
      h[1] = f2bf(fast_tanh(a4[1] + l4[1]));
      h[2] = f2bf(fast_tanh(a4[2] + l4[2]));
      h[3] = f2bf(fast_tanh(a4[3] + l4[3]));
      *(short4v*)&Hs[hr][kk] = h;
    }
    __syncthreads();
    short8 afr0 = *(const short8*)&Hs[ln][q * 8];
    short8 afr1 = *(const short8*)&Hs[16 + ln][q * 8];
    #pragma unroll
    for (int nt = 0; nt < 8; ++nt){
      int col = colBase + nt * 16;
      short8 bfr = *(const short8*)(Wb + (size_t)col * 512 + k0 + q * 8);
      acc[0][nt] = __builtin_amdgcn_mfma_f32_16x16x32_bf16(afr0, bfr, acc[0][nt], 0, 0, 0);
      acc[1][nt] = __builtin_amdgcn_mfma_f32_16x16x32_bf16(afr1, bfr, acc[1][nt], 0, 0, 0);
    }
    __syncthreads();
  }

  // bias add
  #pragma unroll
  for (int nt = 0; nt < 8; ++nt){
    float bc = bias[colBase + nt * 16];
    #pragma unroll
    for (int mt = 0; mt < 2; ++mt)
      #pragma unroll
      for (int r = 0; r < 4; ++r) acc[mt][nt][r] += bc;
  }
  // per-row max
  #pragma unroll
  for (int mt = 0; mt < 2; ++mt)
    #pragma unroll
    for (int r = 0; r < 4; ++r){
      int row = mt * 16 + q * 4 + r;
      float m = acc[mt][0][r];
      #pragma unroll
      for (int nt = 1; nt < 8; ++nt) m = fmaxf(m, acc[mt][nt][r]);
      m = fmaxf(m, __shfl_xor(m, 1, 16));
      m = fmaxf(m, __shfl_xor(m, 2, 16));
      m = fmaxf(m, __shfl_xor(m, 4, 16));
      m = fmaxf(m, __shfl_xor(m, 8, 16));
      if (ln == 0) redM[row][wv] = m;
    }
  __syncthreads();
  if (tid < 32) rowMax[tid] = fmaxf(fmaxf(redM[tid][0], redM[tid][1]),
                                    fmaxf(redM[tid][2], redM[tid][3]));
  __syncthreads();
  // per-row sum of exp
  #pragma unroll
  for (int mt = 0; mt < 2; ++mt)
    #pragma unroll
    for (int r = 0; r < 4; ++r){
      int row = mt * 16 + q * 4 + r;
      float rm = rowMax[row];
      float sa = 0.f;
      #pragma unroll
      for (int nt = 0; nt < 8; ++nt) sa += __expf(acc[mt][nt][r] - rm);
      sa += __shfl_xor(sa, 1, 16);
      sa += __shfl_xor(sa, 2, 16);
      sa += __shfl_xor(sa, 4, 16);
      sa += __shfl_xor(sa, 8, 16);
      if (ln == 0) redS[row][wv] = sa;
    }
  __syncthreads();
  if (tid < 32) rowNorm[tid] = rowMax[tid] +
      __logf(redS[tid][0] + redS[tid][1] + redS[tid][2] + redS[tid][3]);
  __syncthreads();
  // extract logit[0] and logit[sym]
  #pragma unroll
  for (int mt = 0; mt < 2; ++mt)
    #pragma unroll
    for (int nt = 0; nt < 8; ++nt){
      int col = colBase + nt * 16;
      #pragma unroll
      for (int r = 0; r < 4; ++r){
        int row = mt * 16 + q * 4 + r;
        float v = acc[mt][nt][r] - rowNorm[row];
        int gr = r0 + row;
        if (col == 0) pyv[gr] = v;
        if (col == rowSym[row]) pxv[gr] = v;
      }
    }
}

// ---------- scatter band values into diag-major px2d / py2d ----------
__global__ __launch_bounds__(192) void k_band(
    const float* __restrict__ pxv, const float* __restrict__ pyv,
    const int* __restrict__ sbeg, float* __restrict__ px2d, float* __restrict__ py2d)
{
  int bd = blockIdx.x;         // b*640 + d
  int b = bd / 640, d = bd - b * 640;
  int s = threadIdx.x;
  int t = d - s;
  if (s > 128 || t < 0 || t > 512) return;
  size_t addr = ((size_t)b * ROWSA + RBOFF + d) * DPAD + s;
  if (s < 128){
    float v;
    if (t == 512) v = NEGV;
    else {
      int start = sbeg[b * 512 + t];
      int j = s - start;
      v = (j >= 0 && j < 19) ? pxv[((size_t)(b * 512 + t)) * 19 + j] : NEGV;
    }
    px2d[addr] = v;
  }
  if (t <= 511){
    int start = sbeg[b * 512 + t];
    int j = s - start;
    py2d[addr] = (j >= 0 && j < 19) ? pyv[((size_t)(b * 512 + t)) * 19 + j] : NEGV;
  }
}

// ---------- final scalar ----------
__global__ void k_final(const float* __restrict__ tots, const float* __restrict__ totp,
                        float* __restrict__ out){
  if (blockIdx.x == 0 && threadIdx.x == 0){
    float a = 0.f, c = 0.f;
    for (int i = 0; i < 8; ++i){ a += tots[i]; c += totp[i]; }
    out[0] = -0.1f * (a * 0.125f) - (c * 0.125f);
  }
}

extern "C" void kernel_launch(void* const* d_in, const int* in_sizes, int n_in,
                              void* d_out, int out_size, void* d_ws, size_t ws_size,
                              hipStream_t stream){
  (void)in_sizes; (void)n_in; (void)out_size; (void)ws_size;
  const float* am      = (const float*)d_in[0];
  const float* lm      = (const float*)d_in[1];
  const int*   targets = (const int*)d_in[2];
  const float* W       = (const float*)d_in[4];
  const float* bias    = (const float*)d_in[5];
  float* out = (float*)d_out;

  char* base = (char*)d_ws;
  size_t off = 0;
  auto alloc = [&](size_t bytes) -> char* {
    char* r = base + off;
    off += (bytes + 255) & ~(size_t)255;
    return r;
  };
  const size_t DARR = 8ull * ROWSA * DPAD * 4;   // one diag-major array
  float* amMax = (float*)alloc(8ull * 512 * 4);
  float* lmMax = (float*)alloc(8ull * 129 * 4);
  float* lmLse = (float*)alloc(8ull * 129 * 4);
  float* normv = (float*)alloc(8ull * 129 * 512 * 4);
  float* pxd   = (float*)alloc(DARR);
  float* pyd   = (float*)alloc(DARR);
  float* pad   = (float*)alloc(DARR);
  float* betad = (float*)alloc(DARR);
  float* tots  = (float*)alloc(8 * 4);
  float* totp  = (float*)alloc(8 * 4);
  int*   sbr   = (int*)alloc(8ull * 512 * 4);
  int*   sbeg  = (int*)alloc(8ull * 512 * 4);
  float* pxv   = (float*)alloc(8ull * 512 * 19 * 4);
  float* pyv   = (float*)alloc(8ull * 512 * 19 * 4);
  short* Wb    = (short*)alloc(512ull * 512 * 2);
  float* px2d  = pxd;   // alias: pxd/pyd dead after k_window
  float* py2d  = pyd;

  k_row_stats<<<dim3(4096), dim3(256), 0, stream>>>(am, amMax, (float*)nullptr);
  k_row_stats<<<dim3(1032), dim3(256), 0, stream>>>(lm, lmMax, lmLse);
  k_wb<<<dim3(1024), dim3(256), 0, stream>>>(W, Wb);
  k_norm<<<dim3(4, 9, 8), dim3(256), 0, stream>>>(am, lm, lmMax, amMax, normv);
  k_pxpy<<<dim3(1032), dim3(256), 0, stream>>>(am, lm, targets, normv, lmLse, pxd, pyd);
  k_dp_fwd<<<dim3(8), dim3(64), 0, stream>>>(pxd, pyd, pad, tots);
  k_dp_bwd<<<dim3(8), dim3(64), 0, stream>>>(pxd, pyd, betad);
  k_window<<<dim3(64), dim3(256), 0, stream>>>(pxd, pyd, pad, betad, tots, sbr);
  k_adjust<<<dim3(8), dim3(64), 0, stream>>>(sbr, sbeg);
  k_joiner<<<dim3(2432), dim3(256), 0, stream>>>(am, lm, targets, bias, Wb, sbeg, pxv, pyv);
  k_band<<<dim3(5120), dim3(192), 0, stream>>>(pxv, pyv, sbeg, px2d, py2d);
  k_dp_fwd<<<dim3(8), dim3(64), 0, stream>>>(px2d, py2d, (float*)nullptr, totp);
  k_final<<<dim3(1), dim3(64), 0, stream>>>(tots, totp, out);
}

// Round 5
// 642.708 us; speedup vs baseline: 1.8910x; 1.8910x over previous
//
#include <hip/hip_runtime.h>
#include <math.h>

#define NEGV -1e20f
#define DPAD 132      // diag row stride (s index)
#define RBOFF 16      // pad rows before row 0 (bwd prefetch reads to row -15)
#define ROWSA 676     // rows -16..659 (fwd prefetch reads to row 655)
#define RB(p,b) ((p) + ((size_t)(b) * ROWSA + RBOFF) * DPAD)

typedef __attribute__((ext_vector_type(4))) float floatx4;
typedef __attribute__((ext_vector_type(8))) short short8;
typedef __attribute__((ext_vector_type(4))) short short4v;

// B=8, T=512, S=128, C=512, S1=129, T1=513, R=19 (hard-coded for this problem)
// Diagonal-major DP arrays: X[b][d][s] = x[s][t] with d = s+t.

__device__ __forceinline__ float lae(float a, float b){
  float mx = fmaxf(a, b);
  float mn = fminf(a, b);
  return mx + __logf(1.f + __expf(mn - mx));   // exp underflows to 0 for big gaps
}

__device__ __forceinline__ short f2bf(float x){  // f32 -> bf16 RNE
  union { float f; unsigned u; } v; v.f = x;
  unsigned r = v.u + 0x7fffu + ((v.u >> 16) & 1u);
  return (short)(r >> 16);
}

__device__ __forceinline__ float fast_tanh(float x){
  x = fminf(fmaxf(x, -15.f), 15.f);
  float e = __expf(2.f * x);
  return (e - 1.f) / (e + 1.f);
}

// ---------- per-row max (+ optional logsumexp) over C=512 ----------
__global__ __launch_bounds__(256) void k_row_stats(
    const float* __restrict__ in, float* __restrict__ outMax, float* __restrict__ outLse)
{
  int row = blockIdx.x;
  const float* r = in + (size_t)row * 512;
  int tid = threadIdx.x;
  float v0 = r[tid], v1 = r[tid + 256];
  float m = fmaxf(v0, v1);
  #pragma unroll
  for (int off = 32; off; off >>= 1) m = fmaxf(m, __shfl_xor(m, off, 64));
  __shared__ float sm[4];
  __shared__ float sbm;
  int wv = tid >> 6;
  if ((tid & 63) == 0) sm[wv] = m;
  __syncthreads();
  if (tid == 0) sbm = fmaxf(fmaxf(sm[0], sm[1]), fmaxf(sm[2], sm[3]));
  __syncthreads();
  float mx = sbm;
  if (tid == 0) outMax[row] = mx;
  if (outLse){
    float s = __expf(v0 - mx) + __expf(v1 - mx);
    #pragma unroll
    for (int off = 32; off; off >>= 1) s += __shfl_xor(s, off, 64);
    __shared__ float sp[4];
    if ((tid & 63) == 0) sp[wv] = s;
    __syncthreads();
    if (tid == 0) outLse[row] = mx + __logf(sp[0] + sp[1] + sp[2] + sp[3]);
  }
}

// ---------- transpose + bf16-convert joiner_w: Wb[d][c] = bf16(W[c][d]) ----------
__global__ __launch_bounds__(256) void k_wb(const float* __restrict__ W, short* __restrict__ Wb){
  int idx = blockIdx.x * 256 + threadIdx.x;   // 262144 total
  int d = idx >> 9, c = idx & 511;
  Wb[idx] = f2bf(W[c * 512 + d]);
}

// ---------- normalizers: norm[b,s,t] = log(dot(exp(lm-lmmax), exp(am-ammax))) + maxes ----------
__global__ __launch_bounds__(256) void k_norm(
    const float* __restrict__ am, const float* __restrict__ lm,
    const float* __restrict__ lmMax, const float* __restrict__ amMax,
    float* __restrict__ normv)
{
  int b = blockIdx.z;
  int s0 = blockIdx.y * 16;
  int t0 = blockIdx.x * 128;
  __shared__ float lmS[16][68];
  __shared__ float amS[128][68];
  int tid = threadIdx.x;
  int ts = tid >> 4, tt = tid & 15;
  float acc[8];
  #pragma unroll
  for (int j = 0; j < 8; ++j) acc[j] = 0.f;

  for (int k0 = 0; k0 < 512; k0 += 64){
    { // stage lm tile 16x64 (exp fused)
      int e = tid * 4;
      int rr = e >> 6, cc = e & 63;
      int s = s0 + rr;
      floatx4 o = {0.f, 0.f, 0.f, 0.f};
      if (s < 129){
        float mx = lmMax[b * 129 + s];
        floatx4 v = *(const floatx4*)(lm + ((size_t)(b * 129 + s)) * 512 + k0 + cc);
        o[0] = __expf(v[0] - mx); o[1] = __expf(v[1] - mx);
        o[2] = __expf(v[2] - mx); o[3] = __expf(v[3] - mx);
      }
      *(floatx4*)&lmS[rr][cc] = o;
    }
    #pragma unroll
    for (int i = 0; i < 8; ++i){ // stage am tile 128x64 (exp fused)
      int e = (tid + i * 256) * 4;
      int rr = e >> 6, cc = e & 63;
      float mx = amMax[b * 512 + t0 + rr];
      floatx4 v = *(const floatx4*)(am + ((size_t)(b * 512 + t0 + rr)) * 512 + k0 + cc);
      floatx4 o;
      o[0] = __expf(v[0] - mx); o[1] = __expf(v[1] - mx);
      o[2] = __expf(v[2] - mx); o[3] = __expf(v[3] - mx);
      *(floatx4*)&amS[rr][cc] = o;
    }
    __syncthreads();
    #pragma unroll 4
    for (int k = 0; k < 64; ++k){
      float a = lmS[ts][k];
      #pragma unroll
      for (int j = 0; j < 8; ++j) acc[j] += a * amS[tt + 16 * j][k];
    }
    __syncthreads();
  }
  int s = s0 + ts;
  if (s < 129){
    float lmx = lmMax[b * 129 + s];
    #pragma unroll
    for (int j = 0; j < 8; ++j){
      int t = t0 + tt + 16 * j;
      normv[((size_t)(b * 129 + s)) * 512 + t] = __logf(acc[j]) + lmx + amMax[b * 512 + t];
    }
  }
}

// ---------- smoothed px/py, written DIAG-major ----------
__global__ __launch_bounds__(256) void k_pxpy(
    const float* __restrict__ am, const float* __restrict__ lm,
    const int* __restrict__ targets, const float* __restrict__ normv,
    const float* __restrict__ lmLse, float* __restrict__ pxd, float* __restrict__ pyd)
{
  int bs = blockIdx.x;           // b*129 + s
  int b = bs / 129, s = bs % 129;
  float lm0 = lm[(size_t)bs * 512];
  float lse = lmLse[bs];
  int sym = 0; float lms = 0.f;
  if (s < 128){ sym = targets[b * 128 + s]; lms = lm[(size_t)bs * 512 + sym]; }
  const float* nrm = normv + (size_t)bs * 512;
  float* pydb = RB(pyd, b);
  float* pxdb = RB(pxd, b);
  for (int t = threadIdx.x; t < 513; t += 256){
    if (t < 512){
      float n = nrm[t];
      float a0 = am[((size_t)(b * 512 + t)) * 512];
      pydb[(size_t)(s + t) * DPAD + s] = 0.75f * (a0 + lm0 - n) + 0.25f * (lm0 - lse);
      if (s < 128){
        float as = am[((size_t)(b * 512 + t)) * 512 + sym];
        pxdb[(size_t)(s + t) * DPAD + s] = 0.75f * (as + lms - n) + 0.25f * (lms - lse);
      }
    } else if (s < 128){
      pxdb[(size_t)(s + 512) * DPAD + s] = NEGV;
    }
  }
}

// ======================================================================
// One-wave-per-batch systolic lattice DP, software-pipelined in chunks of
// 8 diagonals with two STATIC register buffer sets (loop unrolled by 2
// chunks so every array index is compile-time -> SROA, no rotation movs).
// Loads for chunk c+1 issue at the top of chunk c (8-16 step prefetch
// distance); stores batched at chunk end AFTER next chunk's loads are in
// flight. Lane l owns rows {2l,2l+1} (+row 128 on lane 63); the single
// lane-crossing dependency travels via one ds_bpermute per step.
// ======================================================================

__device__ __forceinline__ void dp_fwd_run(
    const float* __restrict__ pxb, const float* __restrict__ pyb,
    float* __restrict__ pab, float* __restrict__ tot, int b)
{
  int l = threadIdx.x;
  const int a = 2 * l;
  float curA = NEGV, curB = NEGV, curC = NEGV, send = NEGV;
  int paddr = (l - 1) << 2;

  // carry = row -1 operands (garbage pad; all uses guarded)
  float2 cpx = *(const float2*)(pxb - DPAD + a);
  float2 cpy = *(const float2*)(pyb - DPAD + a);
  float  cpz = pyb[-DPAD + 128];

  float2 b0px[8], b0py[8], b1px[8], b1py[8];
  float  b0pz[8], b1pz[8];
  float  outx[8], outy[8], outc[8];

  #pragma unroll
  for (int j = 0; j < 8; ++j){
    b0px[j] = *(const float2*)(pxb + (size_t)j * DPAD + a);
    b0py[j] = *(const float2*)(pyb + (size_t)j * DPAD + a);
    b0pz[j] = pyb[(size_t)j * DPAD + 128];
  }

  for (int i = 0; i < 40; ++i){
    int d0 = i * 16;
    // ---------------- half A: compute rows d0..d0+7 (buf0); load d0+8..15 (buf1)
    #pragma unroll
    for (int j = 0; j < 8; ++j){
      b1px[j] = *(const float2*)(pxb + (size_t)(d0 + 8 + j) * DPAD + a);
      b1py[j] = *(const float2*)(pyb + (size_t)(d0 + 8 + j) * DPAD + a);
      b1pz[j] = pyb[(size_t)(d0 + 8 + j) * DPAD + 128];
    }
    #pragma unroll
    for (int j = 0; j < 8; ++j){
      int d = d0 + j;
      float2 pxm = j ? b0px[j - 1] : cpx;
      float2 pym = j ? b0py[j - 1] : cpy;
      float  pzm = j ? b0pz[j - 1] : cpz;
      float recv = __int_as_float(
          __builtin_amdgcn_ds_bpermute(paddr, __float_as_int(send)));
      int tA = d - a, tC = d - 128;
      float aaA = (l > 0) ? recv : NEGV;
      float bbA = (tA >= 1) ? curA + pym.x : NEGV;
      float nvA = lae(aaA, bbA);
      if (l == 0 && d == 0) nvA = 0.f;
      float aaB = curA + pxm.x;
      float bbB = (tA >= 2) ? curB + pym.y : NEGV;
      float nvB = lae(aaB, bbB);
      float aaC = curB + pxm.y;
      float bbC = (tC >= 1) ? curC + pzm : NEGV;
      float nvC = lae(aaC, bbC);
      if (tA >= 0 && tA <= 512) curA = nvA;
      if (tA >= 1 && tA <= 513) curB = nvB;
      if (tC >= 0 && tC <= 512) curC = nvC;
      send = curB + b0px[j].y;
      outx[j] = curA; outy[j] = curB; outc[j] = curC;
    }
    cpx = b0px[7]; cpy = b0py[7]; cpz = b0pz[7];
    if (pab){
      #pragma unroll
      for (int j = 0; j < 8; ++j)
        *(float2*)(pab + (size_t)(d0 + j) * DPAD + a) = make_float2(outx[j], outy[j]);
      if (l == 63){
        #pragma unroll
        for (int j = 0; j < 8; ++j)
          pab[(size_t)(d0 + j) * DPAD + 128] = outc[j];
      }
    }
    // ---------------- half B: compute rows d0+8..d0+15 (buf1); load d0+16..23 (buf0)
    #pragma unroll
    for (int j = 0; j < 8; ++j){
      b0px[j] = *(const float2*)(pxb + (size_t)(d0 + 16 + j) * DPAD + a);
      b0py[j] = *(const float2*)(pyb + (size_t)(d0 + 16 + j) * DPAD + a);
      b0pz[j] = pyb[(size_t)(d0 + 16 + j) * DPAD + 128];
    }
    #pragma unroll
    for (int j = 0; j < 8; ++j){
      int d = d0 + 8 + j;
      float2 pxm = j ? b1px[j - 1] : cpx;
      float2 pym = j ? b1py[j - 1] : cpy;
      float  pzm = j ? b1pz[j - 1] : cpz;
      float recv = __int_as_float(
          __builtin_amdgcn_ds_bpermute(paddr, __float_as_int(send)));
      int tA = d - a, tC = d - 128;
      float aaA = (l > 0) ? recv : NEGV;
      float bbA = (tA >= 1) ? curA + pym.x : NEGV;
      float nvA = lae(aaA, bbA);
      float aaB = curA + pxm.x;
      float bbB = (tA >= 2) ? curB + pym.y : NEGV;
      float nvB = lae(aaB, bbB);
      float aaC = curB + pxm.y;
      float bbC = (tC >= 1) ? curC + pzm : NEGV;
      float nvC = lae(aaC, bbC);
      if (tA >= 0 && tA <= 512) curA = nvA;
      if (tA >= 1 && tA <= 513) curB = nvB;
      if (tC >= 0 && tC <= 512) curC = nvC;
      send = curB + b1px[j].y;
      outx[j] = curA; outy[j] = curB; outc[j] = curC;
    }
    cpx = b1px[7]; cpy = b1py[7]; cpz = b1pz[7];
    if (pab){
      #pragma unroll
      for (int j = 0; j < 8; ++j)
        *(float2*)(pab + (size_t)(d0 + 8 + j) * DPAD + a) = make_float2(outx[j], outy[j]);
      if (l == 63){
        #pragma unroll
        for (int j = 0; j < 8; ++j)
          pab[(size_t)(d0 + 8 + j) * DPAD + 128] = outc[j];
      }
    }
  }
  // tail: step 640 — only cell C (s=128,t=512) is valid; carry = row 639
  {
    float aaC = curB + cpx.y;
    float bbC = curC + cpz;
    curC = lae(aaC, bbC);
    if (l == 63){
      if (pab) pab[(size_t)640 * DPAD + 128] = curC;
      tot[b] = curC;
    }
  }
}

__device__ __forceinline__ void dp_bwd_run(
    const float* __restrict__ pxb, const float* __restrict__ pyb,
    float* __restrict__ beb)
{
  int l = threadIdx.x;
  const int a = 2 * l;
  float curA = NEGV, curB = NEGV, curC = NEGV, send = NEGV;
  int paddr = (l + 1) << 2;

  float2 b0px[8], b0py[8], b1px[8], b1py[8];
  float  b0pz[8], b1pz[8];
  float  outx[8], outy[8], outc[8];

  #pragma unroll
  for (int j = 0; j < 8; ++j){
    b0px[j] = *(const float2*)(pxb + (size_t)(640 - j) * DPAD + a);
    b0py[j] = *(const float2*)(pyb + (size_t)(640 - j) * DPAD + a);
    b0pz[j] = pyb[(size_t)(640 - j) * DPAD + 128];
  }

  for (int i = 0; i < 40; ++i){
    int d0 = 640 - 16 * i;
    // ---------------- half A: compute rows d0..d0-7 (buf0); load d0-8..d0-15 (buf1)
    #pragma unroll
    for (int j = 0; j < 8; ++j){
      b1px[j] = *(const float2*)(pxb + (size_t)(d0 - 8 - j) * DPAD + a);
      b1py[j] = *(const float2*)(pyb + (size_t)(d0 - 8 - j) * DPAD + a);
      b1pz[j] = pyb[(size_t)(d0 - 8 - j) * DPAD + 128];
    }
    #pragma unroll
    for (int j = 0; j < 8; ++j){
      int d = d0 - j;
      float2 pxA = b0px[j]; float2 pyA = b0py[j]; float pzA = b0pz[j];
      float recv = __int_as_float(
          __builtin_amdgcn_ds_bpermute(paddr, __float_as_int(send)));
      int tA = d - a, tB = tA - 1, tC = d - 128;
      float aaA = pxA.x + curB;
      float bbA = (tA <= 511) ? pyA.x + curA : NEGV;
      float nvA = lae(aaA, bbA);
      float up = (l < 63) ? recv : curC;
      float aaB = pxA.y + up;
      float bbB = (tB <= 511) ? pyA.y + curB : NEGV;
      float nvB = lae(aaB, bbB);
      float nvC = (tC <= 511) ? pzA + curC : NEGV;
      if (tC == 512) nvC = 0.f;
      if (tA >= 0 && tA <= 512) curA = nvA;
      if (tB >= 0 && tB <= 512) curB = nvB;
      if (tC >= 0 && tC <= 512) curC = nvC;
      send = curA;
      outx[j] = curA; outy[j] = curB; outc[j] = curC;
    }
    #pragma unroll
    for (int j = 0; j < 8; ++j)
      *(float2*)(beb + (size_t)(d0 - j) * DPAD + a) = make_float2(outx[j], outy[j]);
    if (l == 63){
      #pragma unroll
      for (int j = 0; j < 8; ++j)
        beb[(size_t)(d0 - j) * DPAD + 128] = outc[j];
    }
    // ---------------- half B: compute rows d0-8..d0-15 (buf1); load d0-16..d0-23 (buf0)
    #pragma unroll
    for (int j = 0; j < 8; ++j){
      b0px[j] = *(const float2*)(pxb + (size_t)(d0 - 16 - j) * DPAD + a);
      b0py[j] = *(const float2*)(pyb + (size_t)(d0 - 16 - j) * DPAD + a);
      b0pz[j] = pyb[(size_t)(d0 - 16 - j) * DPAD + 128];
    }
    #pragma unroll
    for (int j = 0; j < 8; ++j){
      int d = d0 - 8 - j;
      float2 pxA = b1px[j]; float2 pyA = b1py[j]; float pzA = b1pz[j];
      float recv = __int_as_float(
          __builtin_amdgcn_ds_bpermute(paddr, __float_as_int(send)));
      int tA = d - a, tB = tA - 1, tC = d - 128;
      float aaA = pxA.x + curB;
      float bbA = (tA <= 511) ? pyA.x + curA : NEGV;
      float nvA = lae(aaA, bbA);
      float up = (l < 63) ? recv : curC;
      float aaB = pxA.y + up;
      float bbB = (tB <= 511) ? pyA.y + curB : NEGV;
      float nvB = lae(aaB, bbB);
      float nvC = (tC <= 511) ? pzA + curC : NEGV;
      if (tC == 512) nvC = 0.f;
      if (tA >= 0 && tA <= 512) curA = nvA;
      if (tB >= 0 && tB <= 512) curB = nvB;
      if (tC >= 0 && tC <= 512) curC = nvC;
      send = curA;
      outx[j] = curA; outy[j] = curB; outc[j] = curC;
    }
    #pragma unroll
    for (int j = 0; j < 8; ++j)
      *(float2*)(beb + (size_t)(d0 - 8 - j) * DPAD + a) = make_float2(outx[j], outy[j]);
    if (l == 63){
      #pragma unroll
      for (int j = 0; j < 8; ++j)
        beb[(size_t)(d0 - 8 - j) * DPAD + 128] = outc[j];
    }
  }
  // tail: step 0 (row 0 = b0[0] after last half-B load)
  {
    float2 pxA = b0px[0]; float2 pyA = b0py[0]; float pzA = b0pz[0];
    float recv = __int_as_float(
        __builtin_amdgcn_ds_bpermute(paddr, __float_as_int(send)));
    int tA = -a, tB = tA - 1, tC = -128;
    float aaA = pxA.x + curB;
    float bbA = (tA <= 511) ? pyA.x + curA : NEGV;
    float nvA = lae(aaA, bbA);
    float up = (l < 63) ? recv : curC;
    float aaB = pxA.y + up;
    float bbB = (tB <= 511) ? pyA.y + curB : NEGV;
    float nvB = lae(aaB, bbB);
    (void)tC;
    if (tA >= 0 && tA <= 512) curA = nvA;
    if (tB >= 0 && tB <= 512) curB = nvB;
    *(float2*)(beb + a) = make_float2(curA, curB);
    if (l == 63) beb[128] = curC;
  }
}

__global__ __launch_bounds__(64) void k_dp_fb(
    const float* __restrict__ pxd, const float* __restrict__ pyd,
    float* __restrict__ pad, float* __restrict__ betad, float* __restrict__ tots)
{
  int blk = blockIdx.x;
  if (blk < 8){
    int b = blk;
    dp_fwd_run(RB(pxd, b), RB(pyd, b), RB(pad, b), tots, b);
  } else {
    int b = blk - 8;
    dp_bwd_run(RB(pxd, b), RB(pyd, b), RB(betad, b));
  }
}

__global__ __launch_bounds__(64) void k_dp_f2(
    const float* __restrict__ pxd, const float* __restrict__ pyd,
    float* __restrict__ totp)
{
  int b = blockIdx.x;
  dp_fwd_run(RB(pxd, b), RB(pyd, b), (float*)nullptr, totp, b);
}

// ---------- sliding-window argmax over s for each (b,t); grads on the fly ----------
__global__ __launch_bounds__(256) void k_window(
    const float* __restrict__ pxd, const float* __restrict__ pyd,
    const float* __restrict__ pad, const float* __restrict__ betad,
    const float* __restrict__ tots, int* __restrict__ sbr)
{
  __shared__ float tote[129][66];
  int b = blockIdx.x >> 3;
  int t0 = (blockIdx.x & 7) << 6;
  const float* px = RB(pxd, b);
  const float* py = RB(pyd, b);
  const float* pa = RB(pad, b);
  const float* be = RB(betad, b);
  float tv = tots[b];
  int tid = threadIdx.x;
  int wv = tid >> 6, ln = tid & 63;
  for (int dd = wv; dd < 192; dd += 4){
    int d = t0 + dd;
    int slo = dd - 63 > 0 ? dd - 63 : 0;
    int shi = dd < 128 ? dd : 128;
    int s = slo + ln;
    if (s <= shi){
      size_t r0 = (size_t)d * DPAD + s, r1 = (size_t)(d + 1) * DPAD + s;
      float pav = pa[r0];
      float v = __expf(pav + py[r0] + be[r1] - tv);             // gy
      if (s < 128) v += __expf(pav + px[r0] + be[r1 + 1] - tv); // gx
      tote[s][dd - s] = v;
    }
  }
  __syncthreads();
  if (tid < 64){
    int c = tid;
    float win = 0.f;
    for (int s = 0; s < 19; ++s) win += tote[s][c];
    float best = win; int arg = 0;
    for (int w2 = 1; w2 <= 110; ++w2){
      win += tote[w2 + 18][c] - tote[w2 - 1][c];
      if (win > best){ best = win; arg = w2; }   // strict > keeps first-index argmax
    }
    sbr[b * 512 + t0 + c] = arg;
  }
}

// ---------- monotone lower-bound adjust (single reverse pass per batch) ----------
__global__ void k_adjust(const int* __restrict__ sbr, int* __restrict__ sbeg){
  if (threadIdx.x != 0) return;
  int b = blockIdx.x;
  const int* in = sbr + b * 512;
  int* out = sbeg + b * 512;
  int sbm = 1 << 30, ym = 1 << 30;
  for (int t = 511; t >= 0; --t){
    sbm = min(sbm, in[t]);
    int y = 18 * t - sbm;
    ym = min(ym, y);
    int yc = ym > 0 ? ym : 0;
    out[t] = 18 * t - yc;
  }
}

// ---------- joiner: H=tanh(am+lm_pruned) bf16, logits=H@Wb+bias, fused logsumexp epilogue ----------
__global__ __launch_bounds__(256) void k_joiner(
    const float* __restrict__ am, const float* __restrict__ lm,
    const int* __restrict__ targets, const float* __restrict__ bias,
    const short* __restrict__ Wb, const int* __restrict__ sbeg,
    float* __restrict__ pxv, float* __restrict__ pyv)
{
  __shared__ short Hs[32][40];          // 32 rows x 32 k, row stride 40 (bank spread)
  __shared__ int rowSym[32];
  __shared__ int rowAm[32];
  __shared__ int rowLm[32];
  __shared__ float redM[32][4];
  __shared__ float redS[32][4];
  __shared__ float rowMax[32];
  __shared__ float rowNorm[32];

  int tid = threadIdx.x;
  int r0 = blockIdx.x * 32;
  if (tid < 32){
    int row = r0 + tid;
    int g = row / 19;
    int j = row - g * 19;
    int b = g >> 9;
    int t = g & 511;
    int start = sbeg[b * 512 + t];
    int sidx = start + j;               // <= 128 by construction
    rowSym[tid] = (sidx < 128) ? targets[b * 128 + sidx] : 0;
    rowAm[tid] = (b * 512 + t) * 512;
    rowLm[tid] = (b * 129 + sidx) * 512;
  }
  __syncthreads();

  int wv = tid >> 6, lane = tid & 63, q = lane >> 4, ln = lane & 15;
  int colBase = wv * 128 + ln;
  int hr = tid >> 3, kk = (tid & 7) * 4;

  floatx4 acc[2][8];
  #pragma unroll
  for (int mt = 0; mt < 2; ++mt)
    #pragma unroll
    for (int nt = 0; nt < 8; ++nt) acc[mt][nt] = (floatx4){0.f, 0.f, 0.f, 0.f};

  for (int k0 = 0; k0 < 512; k0 += 32){
    { // fused activation staging: 4 elems/thread
      const float* ap = am + (size_t)rowAm[hr] + k0 + kk;
      const float* lp = lm + (size_t)rowLm[hr] + k0 + kk;
      floatx4 a4 = *(const floatx4*)ap;
      floatx4 l4 = *(const floatx4*)lp;
      short4v h;
      h[0] = f2bf(fast_tanh(a4[0] + l4[0]));
      h[1] = f2bf(fast_tanh(a4[1] + l4[1]));
      h[2] = f2bf(fast_tanh(a4[2] + l4[2]));
      h[3] = f2bf(fast_tanh(a4[3] + l4[3]));
      *(short4v*)&Hs[hr][kk] = h;
    }
    __syncthreads();
    short8 afr0 = *(const short8*)&Hs[ln][q * 8];
    short8 afr1 = *(const short8*)&Hs[16 + ln][q * 8];
    #pragma unroll
    for (int nt = 0; nt < 8; ++nt){
      int col = colBase + nt * 16;
      short8 bfr = *(const short8*)(Wb + (size_t)col * 512 + k0 + q * 8);
      acc[0][nt] = __builtin_amdgcn_mfma_f32_16x16x32_bf16(afr0, bfr, acc[0][nt], 0, 0, 0);
      acc[1][nt] = __builtin_amdgcn_mfma_f32_16x16x32_bf16(afr1, bfr, acc[1][nt], 0, 0, 0);
    }
    __syncthreads();
  }

  // bias add
  #pragma unroll
  for (int nt = 0; nt < 8; ++nt){
    float bc = bias[colBase + nt * 16];
    #pragma unroll
    for (int mt = 0; mt < 2; ++mt)
      #pragma unroll
      for (int r = 0; r < 4; ++r) acc[mt][nt][r] += bc;
  }
  // per-row max
  #pragma unroll
  for (int mt = 0; mt < 2; ++mt)
    #pragma unroll
    for (int r = 0; r < 4; ++r){
      int row = mt * 16 + q * 4 + r;
      float m = acc[mt][0][r];
      #pragma unroll
      for (int nt = 1; nt < 8; ++nt) m = fmaxf(m, acc[mt][nt][r]);
      m = fmaxf(m, __shfl_xor(m, 1, 16));
      m = fmaxf(m, __shfl_xor(m, 2, 16));
      m = fmaxf(m, __shfl_xor(m, 4, 16));
      m = fmaxf(m, __shfl_xor(m, 8, 16));
      if (ln == 0) redM[row][wv] = m;
    }
  __syncthreads();
  if (tid < 32) rowMax[tid] = fmaxf(fmaxf(redM[tid][0], redM[tid][1]),
                                    fmaxf(redM[tid][2], redM[tid][3]));
  __syncthreads();
  // per-row sum of exp
  #pragma unroll
  for (int mt = 0; mt < 2; ++mt)
    #pragma unroll
    for (int r = 0; r < 4; ++r){
      int row = mt * 16 + q * 4 + r;
      float rm = rowMax[row];
      float sa = 0.f;
      #pragma unroll
      for (int nt = 0; nt < 8; ++nt) sa += __expf(acc[mt][nt][r] - rm);
      sa += __shfl_xor(sa, 1, 16);
      sa += __shfl_xor(sa, 2, 16);
      sa += __shfl_xor(sa, 4, 16);
      sa += __shfl_xor(sa, 8, 16);
      if (ln == 0) redS[row][wv] = sa;
    }
  __syncthreads();
  if (tid < 32) rowNorm[tid] = rowMax[tid] +
      __logf(redS[tid][0] + redS[tid][1] + redS[tid][2] + redS[tid][3]);
  __syncthreads();
  // extract logit[0] and logit[sym]
  #pragma unroll
  for (int mt = 0; mt < 2; ++mt)
    #pragma unroll
    for (int nt = 0; nt < 8; ++nt){
      int col = colBase + nt * 16;
      #pragma unroll
      for (int r = 0; r < 4; ++r){
        int row = mt * 16 + q * 4 + r;
        float v = acc[mt][nt][r] - rowNorm[row];
        int gr = r0 + row;
        if (col == 0) pyv[gr] = v;
        if (col == rowSym[row]) pxv[gr] = v;
      }
    }
}

// ---------- scatter band values into diag-major px2d / py2d ----------
__global__ __launch_bounds__(192) void k_band(
    const float* __restrict__ pxv, const float* __restrict__ pyv,
    const int* __restrict__ sbeg, float* __restrict__ px2d, float* __restrict__ py2d)
{
  int bd = blockIdx.x;         // b*640 + d
  int b = bd / 640, d = bd - b * 640;
  int s = threadIdx.x;
  int t = d - s;
  if (s > 128 || t < 0 || t > 512) return;
  size_t addr = ((size_t)b * ROWSA + RBOFF + d) * DPAD + s;
  if (s < 128){
    float v;
    if (t == 512) v = NEGV;
    else {
      int start = sbeg[b * 512 + t];
      int j = s - start;
      v = (j >= 0 && j < 19) ? pxv[((size_t)(b * 512 + t)) * 19 + j] : NEGV;
    }
    px2d[addr] = v;
  }
  if (t <= 511){
    int start = sbeg[b * 512 + t];
    int j = s - start;
    py2d[addr] = (j >= 0 && j < 19) ? pyv[((size_t)(b * 512 + t)) * 19 + j] : NEGV;
  }
}

// ---------- final scalar ----------
__global__ void k_final(const float* __restrict__ tots, const float* __restrict__ totp,
                        float* __restrict__ out){
  if (blockIdx.x == 0 && threadIdx.x == 0){
    float a = 0.f, c = 0.f;
    for (int i = 0; i < 8; ++i){ a += tots[i]; c += totp[i]; }
    out[0] = -0.1f * (a * 0.125f) - (c * 0.125f);
  }
}

extern "C" void kernel_launch(void* const* d_in, const int* in_sizes, int n_in,
                              void* d_out, int out_size, void* d_ws, size_t ws_size,
                              hipStream_t stream){
  (void)in_sizes; (void)n_in; (void)out_size; (void)ws_size;
  const float* am      = (const float*)d_in[0];
  const float* lm      = (const float*)d_in[1];
  const int*   targets = (const int*)d_in[2];
  const float* W       = (const float*)d_in[4];
  const float* bias    = (const float*)d_in[5];
  float* out = (float*)d_out;

  char* base = (char*)d_ws;
  size_t off = 0;
  auto alloc = [&](size_t bytes) -> char* {
    char* r = base + off;
    off += (bytes + 255) & ~(size_t)255;
    return r;
  };
  const size_t DARR = 8ull * ROWSA * DPAD * 4;   // one diag-major array
  float* amMax = (float*)alloc(8ull * 512 * 4);
  float* lmMax = (float*)alloc(8ull * 129 * 4);
  float* lmLse = (float*)alloc(8ull * 129 * 4);
  float* normv = (float*)alloc(8ull * 129 * 512 * 4);
  float* pxd   = (float*)alloc(DARR);
  float* pyd   = (float*)alloc(DARR);
  float* pad   = (float*)alloc(DARR);
  float* betad = (float*)alloc(DARR);
  float* tots  = (float*)alloc(8 * 4);
  float* totp  = (float*)alloc(8 * 4);
  int*   sbr   = (int*)alloc(8ull * 512 * 4);
  int*   sbeg  = (int*)alloc(8ull * 512 * 4);
  float* pxv   = (float*)alloc(8ull * 512 * 19 * 4);
  float* pyv   = (float*)alloc(8ull * 512 * 19 * 4);
  short* Wb    = (short*)alloc(512ull * 512 * 2);
  float* px2d  = pxd;   // alias: pxd/pyd dead after k_window
  float* py2d  = pyd;

  k_row_stats<<<dim3(4096), dim3(256), 0, stream>>>(am, amMax, (float*)nullptr);
  k_row_stats<<<dim3(1032), dim3(256), 0, stream>>>(lm, lmMax, lmLse);
  k_wb<<<dim3(1024), dim3(256), 0, stream>>>(W, Wb);
  k_norm<<<dim3(4, 9, 8), dim3(256), 0, stream>>>(am, lm, lmMax, amMax, normv);
  k_pxpy<<<dim3(1032), dim3(256), 0, stream>>>(am, lm, targets, normv, lmLse, pxd, pyd);
  k_dp_fb<<<dim3(16), dim3(64), 0, stream>>>(pxd, pyd, pad, betad, tots);
  k_window<<<dim3(64), dim3(256), 0, stream>>>(pxd, pyd, pad, betad, tots, sbr);
  k_adjust<<<dim3(8), dim3(64), 0, stream>>>(sbr, sbeg);
  k_joiner<<<dim3(2432), dim3(256), 0, stream>>>(am, lm, targets, bias, Wb, sbeg, pxv, pyv);
  k_band<<<dim3(5120), dim3(192), 0, stream>>>(pxv, pyv, sbeg, px2d, py2d);
  k_dp_f2<<<dim3(8), dim3(64), 0, stream>>>(px2d, py2d, totp);
  k_final<<<dim3(1), dim3(64), 0, stream>>>(tots, totp, out);
}

// Round 6
// 632.903 us; speedup vs baseline: 1.9203x; 1.0155x over previous
//
#include <hip/hip_runtime.h>
#include <math.h>

#define NEGV -1e20f
#define DPAD 132      // diag row stride (s index)
#define RBOFF 16      // pad rows before row 0 (bwd prefetch reads to row -15)
#define ROWSA 676     // rows -16..659 (fwd prefetch reads to row 655)
#define RB(p,b) ((p) + ((size_t)(b) * ROWSA + RBOFF) * DPAD)

typedef __attribute__((ext_vector_type(4))) float floatx4;
typedef __attribute__((ext_vector_type(8))) short short8;
typedef __attribute__((ext_vector_type(4))) short short4v;

// B=8, T=512, S=128, C=512, S1=129, T1=513, R=19 (hard-coded for this problem)
// Diagonal-major DP arrays: X[b][d][s] = x[s][t] with d = s+t.

__device__ __forceinline__ float lae(float a, float b){
  float mx = fmaxf(a, b);
  float mn = fminf(a, b);
  return mx + __logf(1.f + __expf(mn - mx));   // exp underflows to 0 for big gaps
}

__device__ __forceinline__ short f2bf(float x){  // f32 -> bf16 RNE
  union { float f; unsigned u; } v; v.f = x;
  unsigned r = v.u + 0x7fffu + ((v.u >> 16) & 1u);
  return (short)(r >> 16);
}

__device__ __forceinline__ float fast_tanh(float x){
  x = fminf(fmaxf(x, -15.f), 15.f);
  float e = __expf(2.f * x);
  return (e - 1.f) / (e + 1.f);
}

// ---------- per-row max (+ optional logsumexp) over C=512 ----------
__global__ __launch_bounds__(256) void k_row_stats(
    const float* __restrict__ in, float* __restrict__ outMax, float* __restrict__ outLse)
{
  int row = blockIdx.x;
  const float* r = in + (size_t)row * 512;
  int tid = threadIdx.x;
  float v0 = r[tid], v1 = r[tid + 256];
  float m = fmaxf(v0, v1);
  #pragma unroll
  for (int off = 32; off; off >>= 1) m = fmaxf(m, __shfl_xor(m, off, 64));
  __shared__ float sm[4];
  __shared__ float sbm;
  int wv = tid >> 6;
  if ((tid & 63) == 0) sm[wv] = m;
  __syncthreads();
  if (tid == 0) sbm = fmaxf(fmaxf(sm[0], sm[1]), fmaxf(sm[2], sm[3]));
  __syncthreads();
  float mx = sbm;
  if (tid == 0) outMax[row] = mx;
  if (outLse){
    float s = __expf(v0 - mx) + __expf(v1 - mx);
    #pragma unroll
    for (int off = 32; off; off >>= 1) s += __shfl_xor(s, off, 64);
    __shared__ float sp[4];
    if ((tid & 63) == 0) sp[wv] = s;
    __syncthreads();
    if (tid == 0) outLse[row] = mx + __logf(sp[0] + sp[1] + sp[2] + sp[3]);
  }
}

// ---------- transpose + bf16-convert joiner_w: Wb[d][c] = bf16(W[c][d]) ----------
__global__ __launch_bounds__(256) void k_wb(const float* __restrict__ W, short* __restrict__ Wb){
  int idx = blockIdx.x * 256 + threadIdx.x;   // 262144 total
  int d = idx >> 9, c = idx & 511;
  Wb[idx] = f2bf(W[c * 512 + d]);
}

// ---------- normalizers: norm[b,s,t] = log(dot(exp(lm-lmmax), exp(am-ammax))) + maxes ----------
__global__ __launch_bounds__(256) void k_norm(
    const float* __restrict__ am, const float* __restrict__ lm,
    const float* __restrict__ lmMax, const float* __restrict__ amMax,
    float* __restrict__ normv)
{
  int b = blockIdx.z;
  int s0 = blockIdx.y * 16;
  int t0 = blockIdx.x * 128;
  __shared__ float lmS[16][68];
  __shared__ float amS[128][68];
  int tid = threadIdx.x;
  int ts = tid >> 4, tt = tid & 15;
  float acc[8];
  #pragma unroll
  for (int j = 0; j < 8; ++j) acc[j] = 0.f;

  for (int k0 = 0; k0 < 512; k0 += 64){
    { // stage lm tile 16x64 (exp fused)
      int e = tid * 4;
      int rr = e >> 6, cc = e & 63;
      int s = s0 + rr;
      floatx4 o = {0.f, 0.f, 0.f, 0.f};
      if (s < 129){
        float mx = lmMax[b * 129 + s];
        floatx4 v = *(const floatx4*)(lm + ((size_t)(b * 129 + s)) * 512 + k0 + cc);
        o[0] = __expf(v[0] - mx); o[1] = __expf(v[1] - mx);
        o[2] = __expf(v[2] - mx); o[3] = __expf(v[3] - mx);
      }
      *(floatx4*)&lmS[rr][cc] = o;
    }
    #pragma unroll
    for (int i = 0; i < 8; ++i){ // stage am tile 128x64 (exp fused)
      int e = (tid + i * 256) * 4;
      int rr = e >> 6, cc = e & 63;
      float mx = amMax[b * 512 + t0 + rr];
      floatx4 v = *(const floatx4*)(am + ((size_t)(b * 512 + t0 + rr)) * 512 + k0 + cc);
      floatx4 o;
      o[0] = __expf(v[0] - mx); o[1] = __expf(v[1] - mx);
      o[2] = __expf(v[2] - mx); o[3] = __expf(v[3] - mx);
      *(floatx4*)&amS[rr][cc] = o;
    }
    __syncthreads();
    #pragma unroll 4
    for (int k = 0; k < 64; ++k){
      float a = lmS[ts][k];
      #pragma unroll
      for (int j = 0; j < 8; ++j) acc[j] += a * amS[tt + 16 * j][k];
    }
    __syncthreads();
  }
  int s = s0 + ts;
  if (s < 129){
    float lmx = lmMax[b * 129 + s];
    #pragma unroll
    for (int j = 0; j < 8; ++j){
      int t = t0 + tt + 16 * j;
      normv[((size_t)(b * 129 + s)) * 512 + t] = __logf(acc[j]) + lmx + amMax[b * 512 + t];
    }
  }
}

// ---------- smoothed px/py, written DIAG-major ----------
__global__ __launch_bounds__(256) void k_pxpy(
    const float* __restrict__ am, const float* __restrict__ lm,
    const int* __restrict__ targets, const float* __restrict__ normv,
    const float* __restrict__ lmLse, float* __restrict__ pxd, float* __restrict__ pyd)
{
  int bs = blockIdx.x;           // b*129 + s
  int b = bs / 129, s = bs % 129;
  float lm0 = lm[(size_t)bs * 512];
  float lse = lmLse[bs];
  int sym = 0; float lms = 0.f;
  if (s < 128){ sym = targets[b * 128 + s]; lms = lm[(size_t)bs * 512 + sym]; }
  const float* nrm = normv + (size_t)bs * 512;
  float* pydb = RB(pyd, b);
  float* pxdb = RB(pxd, b);
  for (int t = threadIdx.x; t < 513; t += 256){
    if (t < 512){
      float n = nrm[t];
      float a0 = am[((size_t)(b * 512 + t)) * 512];
      pydb[(size_t)(s + t) * DPAD + s] = 0.75f * (a0 + lm0 - n) + 0.25f * (lm0 - lse);
      if (s < 128){
        float as = am[((size_t)(b * 512 + t)) * 512 + sym];
        pxdb[(size_t)(s + t) * DPAD + s] = 0.75f * (as + lms - n) + 0.25f * (lms - lse);
      }
    } else if (s < 128){
      pxdb[(size_t)(s + 512) * DPAD + s] = NEGV;
    }
  }
}

// ======================================================================
// One-wave-per-batch systolic lattice DP, software-pipelined in chunks of
// 8 diagonals with two STATIC register buffer sets (loop unrolled by 2
// chunks so every array index is compile-time -> SROA, no rotation movs).
// ======================================================================

__device__ __forceinline__ void dp_fwd_run(
    const float* __restrict__ pxb, const float* __restrict__ pyb,
    float* __restrict__ pab, float* __restrict__ tot, int b)
{
  int l = threadIdx.x;
  const int a = 2 * l;
  float curA = NEGV, curB = NEGV, curC = NEGV, send = NEGV;
  int paddr = (l - 1) << 2;

  // carry = row -1 operands (garbage pad; all uses guarded)
  float2 cpx = *(const float2*)(pxb - DPAD + a);
  float2 cpy = *(const float2*)(pyb - DPAD + a);
  float  cpz = pyb[-DPAD + 128];

  float2 b0px[8], b0py[8], b1px[8], b1py[8];
  float  b0pz[8], b1pz[8];
  float  outx[8], outy[8], outc[8];

  #pragma unroll
  for (int j = 0; j < 8; ++j){
    b0px[j] = *(const float2*)(pxb + (size_t)j * DPAD + a);
    b0py[j] = *(const float2*)(pyb + (size_t)j * DPAD + a);
    b0pz[j] = pyb[(size_t)j * DPAD + 128];
  }

  for (int i = 0; i < 40; ++i){
    int d0 = i * 16;
    #pragma unroll
    for (int j = 0; j < 8; ++j){
      b1px[j] = *(const float2*)(pxb + (size_t)(d0 + 8 + j) * DPAD + a);
      b1py[j] = *(const float2*)(pyb + (size_t)(d0 + 8 + j) * DPAD + a);
      b1pz[j] = pyb[(size_t)(d0 + 8 + j) * DPAD + 128];
    }
    #pragma unroll
    for (int j = 0; j < 8; ++j){
      int d = d0 + j;
      float2 pxm = j ? b0px[j - 1] : cpx;
      float2 pym = j ? b0py[j - 1] : cpy;
      float  pzm = j ? b0pz[j - 1] : cpz;
      float recv = __int_as_float(
          __builtin_amdgcn_ds_bpermute(paddr, __float_as_int(send)));
      int tA = d - a, tC = d - 128;
      float aaA = (l > 0) ? recv : NEGV;
      float bbA = (tA >= 1) ? curA + pym.x : NEGV;
      float nvA = lae(aaA, bbA);
      if (l == 0 && d == 0) nvA = 0.f;
      float aaB = curA + pxm.x;
      float bbB = (tA >= 2) ? curB + pym.y : NEGV;
      float nvB = lae(aaB, bbB);
      float aaC = curB + pxm.y;
      float bbC = (tC >= 1) ? curC + pzm : NEGV;
      float nvC = lae(aaC, bbC);
      if (tA >= 0 && tA <= 512) curA = nvA;
      if (tA >= 1 && tA <= 513) curB = nvB;
      if (tC >= 0 && tC <= 512) curC = nvC;
      send = curB + b0px[j].y;
      outx[j] = curA; outy[j] = curB; outc[j] = curC;
    }
    cpx = b0px[7]; cpy = b0py[7]; cpz = b0pz[7];
    if (pab){
      #pragma unroll
      for (int j = 0; j < 8; ++j)
        *(float2*)(pab + (size_t)(d0 + j) * DPAD + a) = make_float2(outx[j], outy[j]);
      if (l == 63){
        #pragma unroll
        for (int j = 0; j < 8; ++j)
          pab[(size_t)(d0 + j) * DPAD + 128] = outc[j];
      }
    }
    #pragma unroll
    for (int j = 0; j < 8; ++j){
      b0px[j] = *(const float2*)(pxb + (size_t)(d0 + 16 + j) * DPAD + a);
      b0py[j] = *(const float2*)(pyb + (size_t)(d0 + 16 + j) * DPAD + a);
      b0pz[j] = pyb[(size_t)(d0 + 16 + j) * DPAD + 128];
    }
    #pragma unroll
    for (int j = 0; j < 8; ++j){
      int d = d0 + 8 + j;
      float2 pxm = j ? b1px[j - 1] : cpx;
      float2 pym = j ? b1py[j - 1] : cpy;
      float  pzm = j ? b1pz[j - 1] : cpz;
      float recv = __int_as_float(
          __builtin_amdgcn_ds_bpermute(paddr, __float_as_int(send)));
      int tA = d - a, tC = d - 128;
      float aaA = (l > 0) ? recv : NEGV;
      float bbA = (tA >= 1) ? curA + pym.x : NEGV;
      float nvA = lae(aaA, bbA);
      float aaB = curA + pxm.x;
      float bbB = (tA >= 2) ? curB + pym.y : NEGV;
      float nvB = lae(aaB, bbB);
      float aaC = curB + pxm.y;
      float bbC = (tC >= 1) ? curC + pzm : NEGV;
      float nvC = lae(aaC, bbC);
      if (tA >= 0 && tA <= 512) curA = nvA;
      if (tA >= 1 && tA <= 513) curB = nvB;
      if (tC >= 0 && tC <= 512) curC = nvC;
      send = curB + b1px[j].y;
      outx[j] = curA; outy[j] = curB; outc[j] = curC;
    }
    cpx = b1px[7]; cpy = b1py[7]; cpz = b1pz[7];
    if (pab){
      #pragma unroll
      for (int j = 0; j < 8; ++j)
        *(float2*)(pab + (size_t)(d0 + 8 + j) * DPAD + a) = make_float2(outx[j], outy[j]);
      if (l == 63){
        #pragma unroll
        for (int j = 0; j < 8; ++j)
          pab[(size_t)(d0 + 8 + j) * DPAD + 128] = outc[j];
      }
    }
  }
  // tail: step 640 — only cell C (s=128,t=512) is valid; carry = row 639
  {
    float aaC = curB + cpx.y;
    float bbC = curC + cpz;
    curC = lae(aaC, bbC);
    if (l == 63){
      if (pab) pab[(size_t)640 * DPAD + 128] = curC;
      tot[b] = curC;
    }
  }
}

__device__ __forceinline__ void dp_bwd_run(
    const float* __restrict__ pxb, const float* __restrict__ pyb,
    float* __restrict__ beb)
{
  int l = threadIdx.x;
  const int a = 2 * l;
  float curA = NEGV, curB = NEGV, curC = NEGV, send = NEGV;
  int paddr = (l + 1) << 2;

  float2 b0px[8], b0py[8], b1px[8], b1py[8];
  float  b0pz[8], b1pz[8];
  float  outx[8], outy[8], outc[8];

  #pragma unroll
  for (int j = 0; j < 8; ++j){
    b0px[j] = *(const float2*)(pxb + (size_t)(640 - j) * DPAD + a);
    b0py[j] = *(const float2*)(pyb + (size_t)(640 - j) * DPAD + a);
    b0pz[j] = pyb[(size_t)(640 - j) * DPAD + 128];
  }

  for (int i = 0; i < 40; ++i){
    int d0 = 640 - 16 * i;
    #pragma unroll
    for (int j = 0; j < 8; ++j){
      b1px[j] = *(const float2*)(pxb + (size_t)(d0 - 8 - j) * DPAD + a);
      b1py[j] = *(const float2*)(pyb + (size_t)(d0 - 8 - j) * DPAD + a);
      b1pz[j] = pyb[(size_t)(d0 - 8 - j) * DPAD + 128];
    }
    #pragma unroll
    for (int j = 0; j < 8; ++j){
      int d = d0 - j;
      float2 pxA = b0px[j]; float2 pyA = b0py[j]; float pzA = b0pz[j];
      float recv = __int_as_float(
          __builtin_amdgcn_ds_bpermute(paddr, __float_as_int(send)));
      int tA = d - a, tB = tA - 1, tC = d - 128;
      float aaA = pxA.x + curB;
      float bbA = (tA <= 511) ? pyA.x + curA : NEGV;
      float nvA = lae(aaA, bbA);
      float up = (l < 63) ? recv : curC;
      float aaB = pxA.y + up;
      float bbB = (tB <= 511) ? pyA.y + curB : NEGV;
      float nvB = lae(aaB, bbB);
      float nvC = (tC <= 511) ? pzA + curC : NEGV;
      if (tC == 512) nvC = 0.f;
      if (tA >= 0 && tA <= 512) curA = nvA;
      if (tB >= 0 && tB <= 512) curB = nvB;
      if (tC >= 0 && tC <= 512) curC = nvC;
      send = curA;
      outx[j] = curA; outy[j] = curB; outc[j] = curC;
    }
    #pragma unroll
    for (int j = 0; j < 8; ++j)
      *(float2*)(beb + (size_t)(d0 - j) * DPAD + a) = make_float2(outx[j], outy[j]);
    if (l == 63){
      #pragma unroll
      for (int j = 0; j < 8; ++j)
        beb[(size_t)(d0 - j) * DPAD + 128] = outc[j];
    }
    #pragma unroll
    for (int j = 0; j < 8; ++j){
      b0px[j] = *(const float2*)(pxb + (size_t)(d0 - 16 - j) * DPAD + a);
      b0py[j] = *(const float2*)(pyb + (size_t)(d0 - 16 - j) * DPAD + a);
      b0pz[j] = pyb[(size_t)(d0 - 16 - j) * DPAD + 128];
    }
    #pragma unroll
    for (int j = 0; j < 8; ++j){
      int d = d0 - 8 - j;
      float2 pxA = b1px[j]; float2 pyA = b1py[j]; float pzA = b1pz[j];
      float recv = __int_as_float(
          __builtin_amdgcn_ds_bpermute(paddr, __float_as_int(send)));
      int tA = d - a, tB = tA - 1, tC = d - 128;
      float aaA = pxA.x + curB;
      float bbA = (tA <= 511) ? pyA.x + curA : NEGV;
      float nvA = lae(aaA, bbA);
      float up = (l < 63) ? recv : curC;
      float aaB = pxA.y + up;
      float bbB = (tB <= 511) ? pyA.y + curB : NEGV;
      float nvB = lae(aaB, bbB);
      float nvC = (tC <= 511) ? pzA + curC : NEGV;
      if (tC == 512) nvC = 0.f;
      if (tA >= 0 && tA <= 512) curA = nvA;
      if (tB >= 0 && tB <= 512) curB = nvB;
      if (tC >= 0 && tC <= 512) curC = nvC;
      send = curA;
      outx[j] = curA; outy[j] = curB; outc[j] = curC;
    }
    #pragma unroll
    for (int j = 0; j < 8; ++j)
      *(float2*)(beb + (size_t)(d0 - 8 - j) * DPAD + a) = make_float2(outx[j], outy[j]);
    if (l == 63){
      #pragma unroll
      for (int j = 0; j < 8; ++j)
        beb[(size_t)(d0 - 8 - j) * DPAD + 128] = outc[j];
    }
  }
  // tail: step 0
  {
    float2 pxA = b0px[0]; float2 pyA = b0py[0]; float pzA = b0pz[0];
    float recv = __int_as_float(
        __builtin_amdgcn_ds_bpermute(paddr, __float_as_int(send)));
    int tA = -a, tB = tA - 1;
    float aaA = pxA.x + curB;
    float bbA = (tA <= 511) ? pyA.x + curA : NEGV;
    float nvA = lae(aaA, bbA);
    float up = (l < 63) ? recv : curC;
    float aaB = pxA.y + up;
    float bbB = (tB <= 511) ? pyA.y + curB : NEGV;
    float nvB = lae(aaB, bbB);
    (void)pzA;
    if (tA >= 0 && tA <= 512) curA = nvA;
    if (tB >= 0 && tB <= 512) curB = nvB;
    *(float2*)(beb + a) = make_float2(curA, curB);
    if (l == 63) beb[128] = curC;
  }
}

__global__ __launch_bounds__(64) void k_dp_fb(
    const float* __restrict__ pxd, const float* __restrict__ pyd,
    float* __restrict__ pad, float* __restrict__ betad, float* __restrict__ tots)
{
  int blk = blockIdx.x;
  if (blk < 8){
    int b = blk;
    dp_fwd_run(RB(pxd, b), RB(pyd, b), RB(pad, b), tots, b);
  } else {
    int b = blk - 8;
    dp_bwd_run(RB(pxd, b), RB(pyd, b), RB(betad, b));
  }
}

__global__ __launch_bounds__(64) void k_dp_f2(
    const float* __restrict__ pxd, const float* __restrict__ pyd,
    float* __restrict__ totp)
{
  int b = blockIdx.x;
  dp_fwd_run(RB(pxd, b), RB(pyd, b), (float*)nullptr, totp, b);
}

// ---------- sliding-window argmax over s for each (b,t); grads on the fly ----------
__global__ __launch_bounds__(256) void k_window(
    const float* __restrict__ pxd, const float* __restrict__ pyd,
    const float* __restrict__ pad, const float* __restrict__ betad,
    const float* __restrict__ tots, int* __restrict__ sbr)
{
  __shared__ float tote[129][66];
  int b = blockIdx.x >> 3;
  int t0 = (blockIdx.x & 7) << 6;
  const float* px = RB(pxd, b);
  const float* py = RB(pyd, b);
  const float* pa = RB(pad, b);
  const float* be = RB(betad, b);
  float tv = tots[b];
  int tid = threadIdx.x;
  int wv = tid >> 6, ln = tid & 63;
  for (int dd = wv; dd < 192; dd += 4){
    int d = t0 + dd;
    int slo = dd - 63 > 0 ? dd - 63 : 0;
    int shi = dd < 128 ? dd : 128;
    int s = slo + ln;
    if (s <= shi){
      size_t r0 = (size_t)d * DPAD + s, r1 = (size_t)(d + 1) * DPAD + s;
      float pav = pa[r0];
      float v = __expf(pav + py[r0] + be[r1] - tv);             // gy
      if (s < 128) v += __expf(pav + px[r0] + be[r1 + 1] - tv); // gx
      tote[s][dd - s] = v;
    }
  }
  __syncthreads();
  if (tid < 64){
    int c = tid;
    float win = 0.f;
    for (int s = 0; s < 19; ++s) win += tote[s][c];
    float best = win; int arg = 0;
    for (int w2 = 1; w2 <= 110; ++w2){
      win += tote[w2 + 18][c] - tote[w2 - 1][c];
      if (win > best){ best = win; arg = w2; }   // strict > keeps first-index argmax
    }
    sbr[b * 512 + t0 + c] = arg;
  }
}

// ---------- monotone lower-bound adjust (single reverse pass per batch) ----------
__global__ void k_adjust(const int* __restrict__ sbr, int* __restrict__ sbeg){
  if (threadIdx.x != 0) return;
  int b = blockIdx.x;
  const int* in = sbr + b * 512;
  int* out = sbeg + b * 512;
  int sbm = 1 << 30, ym = 1 << 30;
  for (int t = 511; t >= 0; --t){
    sbm = min(sbm, in[t]);
    int y = 18 * t - sbm;
    ym = min(ym, y);
    int yc = ym > 0 ? ym : 0;
    out[t] = 18 * t - yc;
  }
}

// ======================================================================
// joiner v2: 64-row M tile, full-K staged H (one barrier), then an
// uninterrupted MFMA loop (4 m-tiles x 8 n-tiles x 16 k-steps per wave).
// H = tanh(am+lm_pruned) bf16 in LDS; logits = H @ Wb + bias; fused
// logsumexp epilogue; emits only logit[0] and logit[sym].
// ======================================================================
#define JROWS 64
#define HSTR  520   // shorts; 260 words (260%32=4) spreads rows across banks

__global__ __launch_bounds__(256) void k_joiner(
    const float* __restrict__ am, const float* __restrict__ lm,
    const int* __restrict__ targets, const float* __restrict__ bias,
    const short* __restrict__ Wb, const int* __restrict__ sbeg,
    float* __restrict__ pxv, float* __restrict__ pyv)
{
  __shared__ short Hs[JROWS][HSTR];
  __shared__ int rowSym[JROWS];
  __shared__ int rowAm[JROWS];
  __shared__ int rowLm[JROWS];
  __shared__ float redM[JROWS][4];
  __shared__ float redS[JROWS][4];
  __shared__ float rowMax[JROWS];
  __shared__ float rowNorm[JROWS];

  int tid = threadIdx.x;
  int r0 = blockIdx.x * JROWS;
  if (tid < JROWS){
    int row = r0 + tid;
    int g = row / 19;
    int j = row - g * 19;
    int b = g >> 9;
    int t = g & 511;
    int start = sbeg[b * 512 + t];
    int sidx = start + j;               // <= 128 by construction
    rowSym[tid] = (sidx < 128) ? targets[b * 128 + sidx] : 0;
    rowAm[tid] = (b * 512 + t) * 512;
    rowLm[tid] = (b * 129 + sidx) * 512;
  }
  __syncthreads();

  // ---- stage full 64x512 H tile (one pass, deep load pipeline) ----
  {
    int row = tid >> 2;                 // 4 threads per row
    int kb = (tid & 3) * 8;             // thread's 8-k phase; stride 32
    const float* ap = am + (size_t)rowAm[row];
    const float* lp = lm + (size_t)rowLm[row];
    #pragma unroll 4
    for (int i = 0; i < 16; ++i){
      int k = kb + i * 32;
      floatx4 a0 = *(const floatx4*)(ap + k);
      floatx4 a1 = *(const floatx4*)(ap + k + 4);
      floatx4 l0 = *(const floatx4*)(lp + k);
      floatx4 l1 = *(const floatx4*)(lp + k + 4);
      short8 h;
      h[0] = f2bf(fast_tanh(a0[0] + l0[0]));
      h[1] = f2bf(fast_tanh(a0[1] + l0[1]));
      h[2] = f2bf(fast_tanh(a0[2] + l0[2]));
      h[3] = f2bf(fast_tanh(a0[3] + l0[3]));
      h[4] = f2bf(fast_tanh(a1[0] + l1[0]));
      h[5] = f2bf(fast_tanh(a1[1] + l1[1]));
      h[6] = f2bf(fast_tanh(a1[2] + l1[2]));
      h[7] = f2bf(fast_tanh(a1[3] + l1[3]));
      *(short8*)&Hs[row][k] = h;
    }
  }
  __syncthreads();

  int wv = tid >> 6, lane = tid & 63, q = lane >> 4, ln = lane & 15;
  int colBase = wv * 128 + ln;

  floatx4 acc[4][8];
  #pragma unroll
  for (int mt = 0; mt < 4; ++mt)
    #pragma unroll
    for (int nt = 0; nt < 8; ++nt) acc[mt][nt] = (floatx4){0.f, 0.f, 0.f, 0.f};

  // ---- uninterrupted MFMA loop over K ----
  #pragma unroll 2
  for (int k0 = 0; k0 < 512; k0 += 32){
    short8 af[4];
    #pragma unroll
    for (int mt = 0; mt < 4; ++mt)
      af[mt] = *(const short8*)&Hs[mt * 16 + ln][k0 + q * 8];
    #pragma unroll
    for (int nt = 0; nt < 8; ++nt){
      int col = colBase + nt * 16;
      short8 bfr = *(const short8*)(Wb + (size_t)col * 512 + k0 + q * 8);
      #pragma unroll
      for (int mt = 0; mt < 4; ++mt)
        acc[mt][nt] = __builtin_amdgcn_mfma_f32_16x16x32_bf16(af[mt], bfr, acc[mt][nt], 0, 0, 0);
    }
  }

  // bias add
  #pragma unroll
  for (int nt = 0; nt < 8; ++nt){
    float bc = bias[colBase + nt * 16];
    #pragma unroll
    for (int mt = 0; mt < 4; ++mt)
      #pragma unroll
      for (int r = 0; r < 4; ++r) acc[mt][nt][r] += bc;
  }
  // per-row max (across nt in-reg, then across the 16 col-lanes)
  #pragma unroll
  for (int mt = 0; mt < 4; ++mt)
    #pragma unroll
    for (int r = 0; r < 4; ++r){
      int row = mt * 16 + q * 4 + r;
      float m = acc[mt][0][r];
      #pragma unroll
      for (int nt = 1; nt < 8; ++nt) m = fmaxf(m, acc[mt][nt][r]);
      m = fmaxf(m, __shfl_xor(m, 1, 16));
      m = fmaxf(m, __shfl_xor(m, 2, 16));
      m = fmaxf(m, __shfl_xor(m, 4, 16));
      m = fmaxf(m, __shfl_xor(m, 8, 16));
      if (ln == 0) redM[row][wv] = m;
    }
  __syncthreads();
  if (tid < JROWS) rowMax[tid] = fmaxf(fmaxf(redM[tid][0], redM[tid][1]),
                                       fmaxf(redM[tid][2], redM[tid][3]));
  __syncthreads();
  // per-row sum of exp
  #pragma unroll
  for (int mt = 0; mt < 4; ++mt)
    #pragma unroll
    for (int r = 0; r < 4; ++r){
      int row = mt * 16 + q * 4 + r;
      float rm = rowMax[row];
      float sa = 0.f;
      #pragma unroll
      for (int nt = 0; nt < 8; ++nt) sa += __expf(acc[mt][nt][r] - rm);
      sa += __shfl_xor(sa, 1, 16);
      sa += __shfl_xor(sa, 2, 16);
      sa += __shfl_xor(sa, 4, 16);
      sa += __shfl_xor(sa, 8, 16);
      if (ln == 0) redS[row][wv] = sa;
    }
  __syncthreads();
  if (tid < JROWS) rowNorm[tid] = rowMax[tid] +
      __logf(redS[tid][0] + redS[tid][1] + redS[tid][2] + redS[tid][3]);
  __syncthreads();
  // extract logit[0] and logit[sym]
  #pragma unroll
  for (int mt = 0; mt < 4; ++mt)
    #pragma unroll
    for (int nt = 0; nt < 8; ++nt){
      int col = colBase + nt * 16;
      #pragma unroll
      for (int r = 0; r < 4; ++r){
        int row = mt * 16 + q * 4 + r;
        float v = acc[mt][nt][r] - rowNorm[row];
        int gr = r0 + row;
        if (col == 0) pyv[gr] = v;
        if (col == rowSym[row]) pxv[gr] = v;
      }
    }
}

// ---------- scatter band values into diag-major px2d / py2d ----------
__global__ __launch_bounds__(192) void k_band(
    const float* __restrict__ pxv, const float* __restrict__ pyv,
    const int* __restrict__ sbeg, float* __restrict__ px2d, float* __restrict__ py2d)
{
  int bd = blockIdx.x;         // b*640 + d
  int b = bd / 640, d = bd - b * 640;
  int s = threadIdx.x;
  int t = d - s;
  if (s > 128 || t < 0 || t > 512) return;
  size_t addr = ((size_t)b * ROWSA + RBOFF + d) * DPAD + s;
  if (s < 128){
    float v;
    if (t == 512) v = NEGV;
    else {
      int start = sbeg[b * 512 + t];
      int j = s - start;
      v = (j >= 0 && j < 19) ? pxv[((size_t)(b * 512 + t)) * 19 + j] : NEGV;
    }
    px2d[addr] = v;
  }
  if (t <= 511){
    int start = sbeg[b * 512 + t];
    int j = s - start;
    py2d[addr] = (j >= 0 && j < 19) ? pyv[((size_t)(b * 512 + t)) * 19 + j] : NEGV;
  }
}

// ---------- final scalar ----------
__global__ void k_final(const float* __restrict__ tots, const float* __restrict__ totp,
                        float* __restrict__ out){
  if (blockIdx.x == 0 && threadIdx.x == 0){
    float a = 0.f, c = 0.f;
    for (int i = 0; i < 8; ++i){ a += tots[i]; c += totp[i]; }
    out[0] = -0.1f * (a * 0.125f) - (c * 0.125f);
  }
}

extern "C" void kernel_launch(void* const* d_in, const int* in_sizes, int n_in,
                              void* d_out, int out_size, void* d_ws, size_t ws_size,
                              hipStream_t stream){
  (void)in_sizes; (void)n_in; (void)out_size; (void)ws_size;
  const float* am      = (const float*)d_in[0];
  const float* lm      = (const float*)d_in[1];
  const int*   targets = (const int*)d_in[2];
  const float* W       = (const float*)d_in[4];
  const float* bias    = (const float*)d_in[5];
  float* out = (float*)d_out;

  char* base = (char*)d_ws;
  size_t off = 0;
  auto alloc = [&](size_t bytes) -> char* {
    char* r = base + off;
    off += (bytes + 255) & ~(size_t)255;
    return r;
  };
  const size_t DARR = 8ull * ROWSA * DPAD * 4;   // one diag-major array
  float* amMax = (float*)alloc(8ull * 512 * 4);
  float* lmMax = (float*)alloc(8ull * 129 * 4);
  float* lmLse = (float*)alloc(8ull * 129 * 4);
  float* normv = (float*)alloc(8ull * 129 * 512 * 4);
  float* pxd   = (float*)alloc(DARR);
  float* pyd   = (float*)alloc(DARR);
  float* pad   = (float*)alloc(DARR);
  float* betad = (float*)alloc(DARR);
  float* tots  = (float*)alloc(8 * 4);
  float* totp  = (float*)alloc(8 * 4);
  int*   sbr   = (int*)alloc(8ull * 512 * 4);
  int*   sbeg  = (int*)alloc(8ull * 512 * 4);
  float* pxv   = (float*)alloc(8ull * 512 * 19 * 4);
  float* pyv   = (float*)alloc(8ull * 512 * 19 * 4);
  short* Wb    = (short*)alloc(512ull * 512 * 2);
  float* px2d  = pxd;   // alias: pxd/pyd dead after k_window
  float* py2d  = pyd;

  k_row_stats<<<dim3(4096), dim3(256), 0, stream>>>(am, amMax, (float*)nullptr);
  k_row_stats<<<dim3(1032), dim3(256), 0, stream>>>(lm, lmMax, lmLse);
  k_wb<<<dim3(1024), dim3(256), 0, stream>>>(W, Wb);
  k_norm<<<dim3(4, 9, 8), dim3(256), 0, stream>>>(am, lm, lmMax, amMax, normv);
  k_pxpy<<<dim3(1032), dim3(256), 0, stream>>>(am, lm, targets, normv, lmLse, pxd, pyd);
  k_dp_fb<<<dim3(16), dim3(64), 0, stream>>>(pxd, pyd, pad, betad, tots);
  k_window<<<dim3(64), dim3(256), 0, stream>>>(pxd, pyd, pad, betad, tots, sbr);
  k_adjust<<<dim3(8), dim3(64), 0, stream>>>(sbr, sbeg);
  k_joiner<<<dim3(1216), dim3(256), 0, stream>>>(am, lm, targets, bias, Wb, sbeg, pxv, pyv);
  k_band<<<dim3(5120), dim3(192), 0, stream>>>(pxv, pyv, sbeg, px2d, py2d);
  k_dp_f2<<<dim3(8), dim3(64), 0, stream>>>(px2d, py2d, totp);
  k_final<<<dim3(1), dim3(64), 0, stream>>>(tots, totp, out);
}